// Round 14
// baseline (671.751 us; speedup 1.0000x reference)
//
#include <hip/hip_runtime.h>
#include <hip/hip_fp16.h>
#include <math.h>

#define HD 256
#define NHEAD 4
#define CH 64
#define NLAYER 3
#define NEG_SLOPE 0.2f

typedef __attribute__((ext_vector_type(8))) _Float16 half8;
typedef __attribute__((ext_vector_type(4))) _Float16 half4v;
typedef __attribute__((ext_vector_type(4))) float float4v;

// ---------------------------------------------------------------------------
// h0 = x @ Wn + bn_b      (x: [N,9], Wn: [9,256])
// ---------------------------------------------------------------------------
__global__ __launch_bounds__(256) void node_embed_kernel(
    const float* __restrict__ x, const float* __restrict__ Wn,
    const float* __restrict__ bn_b, float* __restrict__ h, int N) {
  int n = blockIdx.x;
  int c = threadIdx.x;
  __shared__ float xs[9];
  if (c < 9) xs[c] = x[(size_t)n * 9 + c];
  __syncthreads();
  float v = bn_b[c];
#pragma unroll
  for (int k = 0; k < 9; ++k) v += xs[k] * Wn[k * HD + c];
  h[(size_t)n * HD + c] = v;
}

// ---------------------------------------------------------------------------
// Fold edge path: Wc[5][12] = We @ w_eff,  bc[12] = be_b @ w_eff.
// 12 blocks, one per (layer, head).
// ---------------------------------------------------------------------------
__global__ __launch_bounds__(256) void precompute_wc_kernel(
    const float* __restrict__ lin_edge_w, const float* __restrict__ att_edge,
    const float* __restrict__ We, const float* __restrict__ be_b,
    float* __restrict__ Wc, float* __restrict__ bc) {
  int lh = blockIdx.x;           // 0..11 = l*4+hh
  int l = lh >> 2, hh = lh & 3;
  __shared__ float weff[256];
  int j = threadIdx.x;
  const float* lw = lin_edge_w + (size_t)l * HD * HD + (size_t)j * HD + hh * CH;
  const float* ae = att_edge + l * HD + hh * CH;
  float s = 0.f;
#pragma unroll 8
  for (int c = 0; c < CH; ++c) s += lw[c] * ae[c];
  weff[j] = s;
  __syncthreads();
  if (j < 5) {
    float acc = 0.f;
    for (int t = 0; t < 256; ++t) acc += We[j * HD + t] * weff[t];
    Wc[j * 12 + lh] = acc;
  } else if (j == 5) {
    float acc = 0.f;
    for (int t = 0; t < 256; ++t) acc += be_b[t] * weff[t];
    bc[lh] = acc;
  }
}

// ---------------------------------------------------------------------------
// Repack lin_w into MFMA B-fragment order, split fp16 hi/lo.
// ---------------------------------------------------------------------------
__global__ __launch_bounds__(64) void conv_bfrag_kernel(
    const float* __restrict__ lin_w, _Float16* __restrict__ Bf_hi,
    _Float16* __restrict__ Bf_lo) {
  int bid = blockIdx.x;            // l*128 + kt*16 + nt
  int l = bid >> 7;
  int kt = (bid >> 4) & 7, nt = bid & 15;
  int lane = threadIdx.x;
  const float* B = lin_w + (size_t)l * HD * HD;
  size_t base = ((size_t)bid * 64 + lane) * 8;
  int k0 = kt * 32 + (lane >> 4) * 8;
  int n = (lane & 15) * 16 + nt;
#pragma unroll
  for (int j = 0; j < 8; ++j) {
    float v = B[(size_t)(k0 + j) * HD + n];
    _Float16 hi = (_Float16)v;
    _Float16 lo = (_Float16)(v - (float)hi);
    Bf_hi[base + j] = hi;
    Bf_lo[base + j] = lo;
  }
}

// ---------------------------------------------------------------------------
// CSR build by destination (col)
// ---------------------------------------------------------------------------
__global__ __launch_bounds__(256) void count_deg_kernel(
    const int* __restrict__ col, int* __restrict__ deg, int E) {
  int e = blockIdx.x * 256 + threadIdx.x;
  if (e < E) atomicAdd(&deg[col[e]], 1);
}

__global__ __launch_bounds__(256) void tile_sums_kernel(
    const int* __restrict__ deg, int* __restrict__ tsum, int N) {
  __shared__ int red[256];
  int i = blockIdx.x * 256 + threadIdx.x;
  red[threadIdx.x] = (i < N) ? deg[i] : 0;
  __syncthreads();
  for (int off = 128; off > 0; off >>= 1) {
    if (threadIdx.x < off) red[threadIdx.x] += red[threadIdx.x + off];
    __syncthreads();
  }
  if (threadIdx.x == 0) tsum[blockIdx.x] = red[0];
}

__global__ __launch_bounds__(64) void scan_tsums_kernel(
    const int* __restrict__ tsum, int* __restrict__ toff, int T) {
  int lane = threadIdx.x;
  int carry = 0;
  for (int base = 0; base < T; base += 64) {
    int i = base + lane;
    int orig = (i < T) ? tsum[i] : 0;
    int v = orig;
#pragma unroll
    for (int off = 1; off < 64; off <<= 1) {
      int t = __shfl_up(v, off, 64);
      if (lane >= off) v += t;
    }
    if (i < T) toff[i] = carry + v - orig;
    carry += __shfl(v, 63, 64);
  }
}

__global__ __launch_bounds__(256) void scan_local_kernel(
    const int* __restrict__ deg, const int* __restrict__ toff,
    int* __restrict__ row_start, int N, int E) {
  __shared__ int buf[256];
  int i = blockIdx.x * 256 + threadIdx.x;
  int v = (i < N) ? deg[i] : 0;
  buf[threadIdx.x] = v;
  __syncthreads();
  for (int off = 1; off < 256; off <<= 1) {
    int t = (threadIdx.x >= off) ? buf[threadIdx.x - off] : 0;
    __syncthreads();
    buf[threadIdx.x] += t;
    __syncthreads();
  }
  if (i < N) row_start[i] = toff[blockIdx.x] + buf[threadIdx.x] - v;
  if (blockIdx.x == 0 && threadIdx.x == 0) row_start[N] = E;
}

// ---------------------------------------------------------------------------
// CSR scatter + fused per-edge a_e for ALL 3 layers (R11 layout — best
// measured: dense rowc + ae4c_all arrays, single kernel).
// ---------------------------------------------------------------------------
__global__ __launch_bounds__(256) void scatter_csr_ae_kernel(
    const int* __restrict__ row, const int* __restrict__ col,
    const float* __restrict__ edge_attr, const int* __restrict__ row_start,
    int* __restrict__ cursor, int* __restrict__ rowc,
    const float* __restrict__ Wc, const float* __restrict__ bc,
    float* __restrict__ ae4c_all, int E) {
  __shared__ float sWc[60];
  __shared__ float sbc[12];
  int t = threadIdx.x;
  if (t < 60) sWc[t] = Wc[t];
  if (t < 12) sbc[t] = bc[t];
  __syncthreads();
  int e = blockIdx.x * 256 + t;
  if (e >= E) return;
  int c = col[e];
  int p = atomicAdd(&cursor[c], 1);
  int slot = row_start[c] + p;
  rowc[slot] = row[e];
  float ea[5];
#pragma unroll
  for (int k = 0; k < 5; ++k) ea[k] = edge_attr[(size_t)e * 5 + k];
#pragma unroll
  for (int l = 0; l < NLAYER; ++l) {
    float av[NHEAD];
#pragma unroll
    for (int hh = 0; hh < NHEAD; ++hh) {
      int lh = l * NHEAD + hh;
      float s = sbc[lh];
#pragma unroll
      for (int k = 0; k < 5; ++k) s += ea[k] * sWc[k * 12 + lh];
      av[hh] = s;
    }
    *(float4*)(ae4c_all + ((size_t)l * E + slot) * 4) =
        make_float4(av[0], av[1], av[2], av[3]);
  }
}

// ---------------------------------------------------------------------------
// MFMA split-fp16 GEMM, fused epilogue. 128 rows/block (8 waves, 512 thr).
// Bhi staged in LDS (16 KB/kt, shared by 8 waves); Blo read DIRECTLY from
// L2 (Bf_lo is 128 KB/layer, L2-resident) — halves LDS port traffic vs
// staging both.
// ---------------------------------------------------------------------------
__global__ __launch_bounds__(512) void mfma_gemm_fused_kernel(
    const float* __restrict__ A, const _Float16* __restrict__ Bf_hi,
    const _Float16* __restrict__ Bf_lo, const float* __restrict__ att_s,
    const float* __restrict__ att_d, __half* __restrict__ xh_h,
    float* __restrict__ a_src, float* __restrict__ a_dst, int N) {
  __shared__ _Float16 sBh[8192];  // 16 KB kt-slice of Bf_hi
  const int tid = threadIdx.x;
  const int wave = tid >> 6, lane = tid & 63;
  const int m = lane & 15, quad = lane >> 4;
  const int rowbase = blockIdx.x * 128 + wave * 16;
  const int arow = rowbase + m;
  const int arowc = (arow < N) ? arow : (N - 1);

  float4v acc[16];
#pragma unroll
  for (int nt = 0; nt < 16; ++nt) acc[nt] = (float4v){0.f, 0.f, 0.f, 0.f};

  for (int kt = 0; kt < 8; ++kt) {
    __syncthreads();  // previous iteration's LDS reads done
    {
      const float4* gh = (const float4*)(Bf_hi + (size_t)kt * 8192);
      float4* dh = (float4*)sBh;
      dh[tid] = gh[tid];
      dh[tid + 512] = gh[tid + 512];
    }
    const float* ap = A + (size_t)arowc * HD + kt * 32 + quad * 8;
    float4 av0 = *(const float4*)(ap);
    float4 av1 = *(const float4*)(ap + 4);
    float af[8] = {av0.x, av0.y, av0.z, av0.w, av1.x, av1.y, av1.z, av1.w};
    half8 ahi, alo;
#pragma unroll
    for (int j = 0; j < 8; ++j) {
      _Float16 hi = (_Float16)af[j];
      ahi[j] = hi;
      alo[j] = (_Float16)(af[j] - (float)hi);
    }
    const _Float16* blp = Bf_lo + (((size_t)kt * 16) * 64 + lane) * 8;
    __syncthreads();  // staging complete
#pragma unroll
    for (int nt = 0; nt < 16; ++nt) {
      half8 bhi = *(const half8*)&sBh[nt * 512 + lane * 8];
      half8 blo = *(const half8*)(blp + (size_t)nt * 512);
      acc[nt] = __builtin_amdgcn_mfma_f32_16x16x32_f16(ahi, bhi, acc[nt], 0, 0, 0);
      acc[nt] = __builtin_amdgcn_mfma_f32_16x16x32_f16(alo, bhi, acc[nt], 0, 0, 0);
      acc[nt] = __builtin_amdgcn_mfma_f32_16x16x32_f16(ahi, blo, acc[nt], 0, 0, 0);
    }
  }

  const int hh = m >> 2;
  float ats[16], atd[16];
#pragma unroll
  for (int nt = 0; nt < 16; ++nt) {
    ats[nt] = att_s[m * 16 + nt];
    atd[nt] = att_d[m * 16 + nt];
  }
  _Float16* xf = (_Float16*)xh_h;
#pragma unroll
  for (int r = 0; r < 4; ++r) {
    int orow = rowbase + quad * 4 + r;
    bool valid = orow < N;
    float ps = 0.f, pd = 0.f;
    half8 h0, h1;
#pragma unroll
    for (int nt = 0; nt < 8; ++nt) {
      h0[nt] = (_Float16)acc[nt][r];
      h1[nt] = (_Float16)acc[nt + 8][r];
      ps += acc[nt][r] * ats[nt] + acc[nt + 8][r] * ats[nt + 8];
      pd += acc[nt][r] * atd[nt] + acc[nt + 8][r] * atd[nt + 8];
    }
    if (valid) {
      _Float16* dst = xf + (size_t)orow * HD + m * 16;
      *(half8*)dst = h0;
      *(half8*)(dst + 8) = h1;
    }
    ps += __shfl_xor(ps, 1, 64);
    ps += __shfl_xor(ps, 2, 64);
    pd += __shfl_xor(pd, 1, 64);
    pd += __shfl_xor(pd, 2, 64);
    if (valid && (m & 3) == 0) {
      a_src[(size_t)orow * NHEAD + hh] = ps;
      a_dst[(size_t)orow * NHEAD + hh] = pd;
    }
  }
}

// ---------------------------------------------------------------------------
// Fused softmax + gather-aggregate (R11 dense-array layout — best measured).
// 4 nodes/block, 1 wave/node. Pass 1: online softmax. Pass 2: cooperative
// weights + broadcast + 16 row-gathers in flight.
// ---------------------------------------------------------------------------
__global__ __launch_bounds__(256) void fused_aggregate_kernel(
    const __half* __restrict__ xh_h, const int* __restrict__ rowc,
    const int* __restrict__ row_start, const float* __restrict__ ae4c_l,
    const float* __restrict__ a_src, const float* __restrict__ a_dst,
    const float* __restrict__ cb, const float* __restrict__ gm,
    const float* __restrict__ bt, float inv_std, float* __restrict__ hout,
    int N) {
  int tid = threadIdx.x;
  int n = blockIdx.x * 4 + (tid >> 6);
  if (n >= N) return;
  int lane = tid & 63;
  int s = row_start[n], e = row_start[n + 1];

  int hh1 = lane & 3, j = lane >> 2;
  float based1 = a_dst[n * 4 + hh1];
  float m = -3e38f, ssum = 0.f, aes = 0.f;
  for (int i = s + j; i < e; i += 16) {
    int r = rowc[i];
    float ae = ae4c_l[(size_t)i * 4 + hh1];
    float lg = a_src[r * 4 + hh1] + based1 + ae;
    lg = (lg >= 0.f) ? lg : NEG_SLOPE * lg;
    aes += ae;
    float mn = fmaxf(m, lg);
    ssum = ssum * __expf(m - mn) + __expf(lg - mn);
    m = mn;
  }
#pragma unroll
  for (int off = 4; off < 64; off <<= 1) {
    float m2 = __shfl_xor(m, off, 64);
    float s2 = __shfl_xor(ssum, off, 64);
    aes += __shfl_xor(aes, off, 64);
    float mn = fmaxf(m, m2);
    ssum = ssum * __expf(m - mn) + s2 * __expf(m2 - mn);
    m = mn;
  }
  float dinv = (e > s) ? 1.0f / (float)(e - s) : 1.0f;
  float sl = a_src[n * 4 + hh1] + based1 + aes * dinv;
  sl = (sl >= 0.f) ? sl : NEG_SLOPE * sl;
  float mfin = fmaxf(m, sl);
  float self_e = __expf(sl - mfin);
  float tot = ssum * __expf(m - mfin) + self_e;
  float is = 1.0f / (tot + 1e-16f);
  float selfw = self_e * is;

  int hw = lane >> 4;
  float m_h = __shfl(mfin, hw, 64);
  float is_h = __shfl(is, hw, 64);
  float sw_h = __shfl(selfw, hw, 64);
  float based2 = a_dst[n * 4 + hw];

  int eidx = lane & 15;
  int t = lane;
  int ch = t * 4;
  const half4v* xh4 = (const half4v*)xh_h;

  half4v sv = xh4[(size_t)n * 64 + t];
  float a0 = sw_h * (float)sv[0], a1 = sw_h * (float)sv[1];
  float a2 = sw_h * (float)sv[2], a3 = sw_h * (float)sv[3];

  const int base_src = lane & 48;
  for (int chunk = s; chunk < e; chunk += 16) {
    int myedge = chunk + eidx;
    int r_my = 0;
    float w_my = 0.f;
    if (myedge < e) {
      r_my = rowc[myedge];
      float lg = a_src[r_my * 4 + hw] + based2 + ae4c_l[(size_t)myedge * 4 + hw];
      lg = (lg >= 0.f) ? lg : NEG_SLOPE * lg;
      w_my = __expf(lg - m_h) * is_h;
    }
#pragma unroll
    for (int u = 0; u < 16; ++u) {
      float w = __shfl(w_my, base_src + u, 64);
      int ru = __shfl(r_my, base_src + u, 64);
      half4v xv = xh4[(size_t)ru * 64 + t];
      a0 += w * (float)xv[0];
      a1 += w * (float)xv[1];
      a2 += w * (float)xv[2];
      a3 += w * (float)xv[3];
    }
  }
  float4 outv;
  outv.x = fmaxf((a0 + cb[ch + 0]) * inv_std * gm[ch + 0] + bt[ch + 0], 0.f);
  outv.y = fmaxf((a1 + cb[ch + 1]) * inv_std * gm[ch + 1] + bt[ch + 1], 0.f);
  outv.z = fmaxf((a2 + cb[ch + 2]) * inv_std * gm[ch + 2] + bt[ch + 2], 0.f);
  outv.w = fmaxf((a3 + cb[ch + 3]) * inv_std * gm[ch + 3] + bt[ch + 3], 0.f);
  *(float4*)&hout[(size_t)n * HD + ch] = outv;
}

// ---------------------------------------------------------------------------
// Global mean pool over sorted batch ids. Grid (G, 2), 128 ch per block.
// ---------------------------------------------------------------------------
__global__ __launch_bounds__(128) void pool_kernel(
    const float* __restrict__ h, const int* __restrict__ batch,
    float* __restrict__ out, int N) {
  int g = blockIdx.x;
  int ch = blockIdx.y * 128 + threadIdx.x;
  __shared__ int s_lo, s_hi;
  if (threadIdx.x == 0) {
    int lo = 0, hi = N;
    while (lo < hi) { int mid = (lo + hi) >> 1; if (batch[mid] < g) lo = mid + 1; else hi = mid; }
    s_lo = lo;
    lo = 0; hi = N;
    while (lo < hi) { int mid = (lo + hi) >> 1; if (batch[mid] < g + 1) lo = mid + 1; else hi = mid; }
    s_hi = lo;
  }
  __syncthreads();
  int lo = s_lo, hi = s_hi;
  float acc = 0.f;
  for (int n = lo; n < hi; ++n) acc += h[(size_t)n * HD + ch];
  int cnt = hi - lo;
  out[(size_t)g * HD + ch] = acc / (float)(cnt > 0 ? cnt : 1);
}

// ---------------------------------------------------------------------------
extern "C" void kernel_launch(void* const* d_in, const int* in_sizes, int n_in,
                              void* d_out, int out_size, void* d_ws, size_t ws_size,
                              hipStream_t stream) {
  const float* x = (const float*)d_in[0];
  const int* ei = (const int*)d_in[1];
  const float* edge_attr = (const float*)d_in[2];
  const int* batch = (const int*)d_in[3];
  const float* Wn = (const float*)d_in[4];
  const float* bn_b = (const float*)d_in[5];
  const float* We = (const float*)d_in[6];
  const float* be_b = (const float*)d_in[7];
  const float* lin_w = (const float*)d_in[8];
  const float* att_src = (const float*)d_in[9];
  const float* att_dst = (const float*)d_in[10];
  const float* lin_edge_w = (const float*)d_in[11];
  const float* att_edge = (const float*)d_in[12];
  const float* conv_bias = (const float*)d_in[13];
  const float* gamma = (const float*)d_in[14];
  const float* beta = (const float*)d_in[15];

  const int N = in_sizes[3];
  const int E = in_sizes[1] / 2;
  const int G = out_size / HD;
  const int* row = ei;
  const int* col = ei + E;

  char* ws = (char*)d_ws;
  size_t off = 0;
  auto alloc = [&](size_t bytes) -> char* {
    char* p = ws + off;
    off += (bytes + 255) & ~(size_t)255;
    return p;
  };
  float* h = (float*)alloc((size_t)N * HD * 4);
  __half* xh_h = (__half*)alloc((size_t)N * HD * 2);
  float* a_src = (float*)alloc((size_t)N * NHEAD * 4);
  float* a_dst = (float*)alloc((size_t)N * NHEAD * 4);
  float* ae4c_all = (float*)alloc((size_t)NLAYER * E * NHEAD * 4);
  int* deg = (int*)alloc((size_t)N * 4);
  int* row_start = (int*)alloc((size_t)(N + 1) * 4);
  int* cursor = (int*)alloc((size_t)N * 4);
  int* rowc = (int*)alloc((size_t)E * 4);
  int* tsum = (int*)alloc(4096);
  int* toff = (int*)alloc(4096);
  float* Wc = (float*)alloc(64 * 4);
  float* bc = (float*)alloc(16 * 4);
  _Float16* Bf_hi = (_Float16*)alloc((size_t)NLAYER * HD * HD * 2);
  _Float16* Bf_lo = (_Float16*)alloc((size_t)NLAYER * HD * HD * 2);

  hipMemsetAsync(deg, 0, (size_t)N * 4, stream);
  hipMemsetAsync(cursor, 0, (size_t)N * 4, stream);

  node_embed_kernel<<<N, 256, 0, stream>>>(x, Wn, bn_b, h, N);
  precompute_wc_kernel<<<12, 256, 0, stream>>>(lin_edge_w, att_edge, We, be_b, Wc, bc);
  conv_bfrag_kernel<<<NLAYER * 128, 64, 0, stream>>>(lin_w, Bf_hi, Bf_lo);
  count_deg_kernel<<<(E + 255) / 256, 256, 0, stream>>>(col, deg, E);
  int T = (N + 255) / 256;
  tile_sums_kernel<<<T, 256, 0, stream>>>(deg, tsum, N);
  scan_tsums_kernel<<<1, 64, 0, stream>>>(tsum, toff, T);
  scan_local_kernel<<<T, 256, 0, stream>>>(deg, toff, row_start, N, E);
  scatter_csr_ae_kernel<<<(E + 255) / 256, 256, 0, stream>>>(
      row, col, edge_attr, row_start, cursor, rowc, Wc, bc, ae4c_all, E);

  const float inv_std = 1.0f / sqrtf(1.0f + 1e-5f);
  for (int l = 0; l < NLAYER; ++l) {
    mfma_gemm_fused_kernel<<<(N + 127) / 128, 512, 0, stream>>>(
        h, Bf_hi + (size_t)l * HD * HD, Bf_lo + (size_t)l * HD * HD,
        att_src + l * HD, att_dst + l * HD, xh_h, a_src, a_dst, N);
    fused_aggregate_kernel<<<(N + 3) / 4, 256, 0, stream>>>(
        xh_h, rowc, row_start, ae4c_all + (size_t)l * E * NHEAD, a_src, a_dst,
        conv_bias + l * HD, gamma + l * HD, beta + l * HD, inv_std, h, N);
  }
  dim3 pg(G, 2);
  pool_kernel<<<pg, 128, 0, stream>>>(h, batch, (float*)d_out, N);
}

// Round 15
// 574.744 us; speedup vs baseline: 1.1688x; 1.1688x over previous
//
#include <hip/hip_runtime.h>
#include <hip/hip_fp16.h>
#include <math.h>

#define HD 256
#define NHEAD 4
#define CH 64
#define NLAYER 3
#define NEG_SLOPE 0.2f

typedef __attribute__((ext_vector_type(8))) _Float16 half8;
typedef __attribute__((ext_vector_type(4))) _Float16 half4v;
typedef __attribute__((ext_vector_type(4))) float float4v;

// ---------------------------------------------------------------------------
// h0 = x @ Wn + bn_b      (x: [N,9], Wn: [9,256])
// ---------------------------------------------------------------------------
__global__ __launch_bounds__(256) void node_embed_kernel(
    const float* __restrict__ x, const float* __restrict__ Wn,
    const float* __restrict__ bn_b, float* __restrict__ h, int N) {
  int n = blockIdx.x;
  int c = threadIdx.x;
  __shared__ float xs[9];
  if (c < 9) xs[c] = x[(size_t)n * 9 + c];
  __syncthreads();
  float v = bn_b[c];
#pragma unroll
  for (int k = 0; k < 9; ++k) v += xs[k] * Wn[k * HD + c];
  h[(size_t)n * HD + c] = v;
}

// ---------------------------------------------------------------------------
// Fold edge path: Wc[5][12] = We @ w_eff,  bc[12] = be_b @ w_eff.
// 12 blocks, one per (layer, head).
// ---------------------------------------------------------------------------
__global__ __launch_bounds__(256) void precompute_wc_kernel(
    const float* __restrict__ lin_edge_w, const float* __restrict__ att_edge,
    const float* __restrict__ We, const float* __restrict__ be_b,
    float* __restrict__ Wc, float* __restrict__ bc) {
  int lh = blockIdx.x;           // 0..11 = l*4+hh
  int l = lh >> 2, hh = lh & 3;
  __shared__ float weff[256];
  int j = threadIdx.x;
  const float* lw = lin_edge_w + (size_t)l * HD * HD + (size_t)j * HD + hh * CH;
  const float* ae = att_edge + l * HD + hh * CH;
  float s = 0.f;
#pragma unroll 8
  for (int c = 0; c < CH; ++c) s += lw[c] * ae[c];
  weff[j] = s;
  __syncthreads();
  if (j < 5) {
    float acc = 0.f;
    for (int t = 0; t < 256; ++t) acc += We[j * HD + t] * weff[t];
    Wc[j * 12 + lh] = acc;
  } else if (j == 5) {
    float acc = 0.f;
    for (int t = 0; t < 256; ++t) acc += be_b[t] * weff[t];
    bc[lh] = acc;
  }
}

// ---------------------------------------------------------------------------
// Repack lin_w into MFMA B-fragment order, fp16 (hi only — the dropped lo
// term contributes ~2^-12 RMS relative, same scale as the fp16 xh store).
// Interleaved col map: fragment (l,kt,nt), lane -> B[kt*32+(lane>>4)*8+j][(lane&15)*16+nt]
// ---------------------------------------------------------------------------
__global__ __launch_bounds__(64) void conv_bfrag_kernel(
    const float* __restrict__ lin_w, _Float16* __restrict__ Bf_hi) {
  int bid = blockIdx.x;            // l*128 + kt*16 + nt
  int l = bid >> 7;
  int kt = (bid >> 4) & 7, nt = bid & 15;
  int lane = threadIdx.x;
  const float* B = lin_w + (size_t)l * HD * HD;
  size_t base = ((size_t)bid * 64 + lane) * 8;
  int k0 = kt * 32 + (lane >> 4) * 8;
  int n = (lane & 15) * 16 + nt;
#pragma unroll
  for (int j = 0; j < 8; ++j) {
    Bf_hi[base + j] = (_Float16)B[(size_t)(k0 + j) * HD + n];
  }
}

// ---------------------------------------------------------------------------
// CSR build by destination (col)
// ---------------------------------------------------------------------------
__global__ __launch_bounds__(256) void count_deg_kernel(
    const int* __restrict__ col, int* __restrict__ deg, int E) {
  int e = blockIdx.x * 256 + threadIdx.x;
  if (e < E) atomicAdd(&deg[col[e]], 1);
}

__global__ __launch_bounds__(256) void tile_sums_kernel(
    const int* __restrict__ deg, int* __restrict__ tsum, int N) {
  __shared__ int red[256];
  int i = blockIdx.x * 256 + threadIdx.x;
  red[threadIdx.x] = (i < N) ? deg[i] : 0;
  __syncthreads();
  for (int off = 128; off > 0; off >>= 1) {
    if (threadIdx.x < off) red[threadIdx.x] += red[threadIdx.x + off];
    __syncthreads();
  }
  if (threadIdx.x == 0) tsum[blockIdx.x] = red[0];
}

__global__ __launch_bounds__(64) void scan_tsums_kernel(
    const int* __restrict__ tsum, int* __restrict__ toff, int T) {
  int lane = threadIdx.x;
  int carry = 0;
  for (int base = 0; base < T; base += 64) {
    int i = base + lane;
    int orig = (i < T) ? tsum[i] : 0;
    int v = orig;
#pragma unroll
    for (int off = 1; off < 64; off <<= 1) {
      int t = __shfl_up(v, off, 64);
      if (lane >= off) v += t;
    }
    if (i < T) toff[i] = carry + v - orig;
    carry += __shfl(v, 63, 64);
  }
}

__global__ __launch_bounds__(256) void scan_local_kernel(
    const int* __restrict__ deg, const int* __restrict__ toff,
    int* __restrict__ row_start, int N, int E) {
  __shared__ int buf[256];
  int i = blockIdx.x * 256 + threadIdx.x;
  int v = (i < N) ? deg[i] : 0;
  buf[threadIdx.x] = v;
  __syncthreads();
  for (int off = 1; off < 256; off <<= 1) {
    int t = (threadIdx.x >= off) ? buf[threadIdx.x - off] : 0;
    __syncthreads();
    buf[threadIdx.x] += t;
    __syncthreads();
  }
  if (i < N) row_start[i] = toff[blockIdx.x] + buf[threadIdx.x] - v;
  if (blockIdx.x == 0 && threadIdx.x == 0) row_start[N] = E;
}

// ---------------------------------------------------------------------------
// CSR scatter + fused per-edge a_e for ALL 3 layers (R11 layout — best
// measured: dense rowc + ae4c_all arrays, single kernel).
// ---------------------------------------------------------------------------
__global__ __launch_bounds__(256) void scatter_csr_ae_kernel(
    const int* __restrict__ row, const int* __restrict__ col,
    const float* __restrict__ edge_attr, const int* __restrict__ row_start,
    int* __restrict__ cursor, int* __restrict__ rowc,
    const float* __restrict__ Wc, const float* __restrict__ bc,
    float* __restrict__ ae4c_all, int E) {
  __shared__ float sWc[60];
  __shared__ float sbc[12];
  int t = threadIdx.x;
  if (t < 60) sWc[t] = Wc[t];
  if (t < 12) sbc[t] = bc[t];
  __syncthreads();
  int e = blockIdx.x * 256 + t;
  if (e >= E) return;
  int c = col[e];
  int p = atomicAdd(&cursor[c], 1);
  int slot = row_start[c] + p;
  rowc[slot] = row[e];
  float ea[5];
#pragma unroll
  for (int k = 0; k < 5; ++k) ea[k] = edge_attr[(size_t)e * 5 + k];
#pragma unroll
  for (int l = 0; l < NLAYER; ++l) {
    float av[NHEAD];
#pragma unroll
    for (int hh = 0; hh < NHEAD; ++hh) {
      int lh = l * NHEAD + hh;
      float s = sbc[lh];
#pragma unroll
      for (int k = 0; k < 5; ++k) s += ea[k] * sWc[k * 12 + lh];
      av[hh] = s;
    }
    *(float4*)(ae4c_all + ((size_t)l * E + slot) * 4) =
        make_float4(av[0], av[1], av[2], av[3]);
  }
}

// ---------------------------------------------------------------------------
// MFMA split-fp16 GEMM (A: fp32 via hi+lo; B: fp16). 128 rows/block (8
// waves, 512 thr); per-kt Bhi staged once in 16 KB LDS shared by all waves.
// 2 MFMAs per (kt,nt): Ahi·B + Alo·B. Dropped Ahi·Blo term ~2^-12 RMS rel.
// ---------------------------------------------------------------------------
__global__ __launch_bounds__(512) void mfma_gemm_fused_kernel(
    const float* __restrict__ A, const _Float16* __restrict__ Bf_hi,
    const float* __restrict__ att_s, const float* __restrict__ att_d,
    __half* __restrict__ xh_h, float* __restrict__ a_src,
    float* __restrict__ a_dst, int N) {
  __shared__ _Float16 sBh[8192];  // 16 KB kt-slice of Bf_hi
  const int tid = threadIdx.x;
  const int wave = tid >> 6, lane = tid & 63;
  const int m = lane & 15, quad = lane >> 4;
  const int rowbase = blockIdx.x * 128 + wave * 16;
  const int arow = rowbase + m;
  const int arowc = (arow < N) ? arow : (N - 1);

  float4v acc[16];
#pragma unroll
  for (int nt = 0; nt < 16; ++nt) acc[nt] = (float4v){0.f, 0.f, 0.f, 0.f};

  for (int kt = 0; kt < 8; ++kt) {
    __syncthreads();  // previous iteration's LDS reads done
    {
      const float4* gh = (const float4*)(Bf_hi + (size_t)kt * 8192);
      float4* dh = (float4*)sBh;
      dh[tid] = gh[tid];
      dh[tid + 512] = gh[tid + 512];
    }
    const float* ap = A + (size_t)arowc * HD + kt * 32 + quad * 8;
    float4 av0 = *(const float4*)(ap);
    float4 av1 = *(const float4*)(ap + 4);
    float af[8] = {av0.x, av0.y, av0.z, av0.w, av1.x, av1.y, av1.z, av1.w};
    half8 ahi, alo;
#pragma unroll
    for (int j = 0; j < 8; ++j) {
      _Float16 hi = (_Float16)af[j];
      ahi[j] = hi;
      alo[j] = (_Float16)(af[j] - (float)hi);
    }
    __syncthreads();  // staging complete
#pragma unroll
    for (int nt = 0; nt < 16; ++nt) {
      half8 bhi = *(const half8*)&sBh[nt * 512 + lane * 8];
      acc[nt] = __builtin_amdgcn_mfma_f32_16x16x32_f16(ahi, bhi, acc[nt], 0, 0, 0);
      acc[nt] = __builtin_amdgcn_mfma_f32_16x16x32_f16(alo, bhi, acc[nt], 0, 0, 0);
    }
  }

  const int hh = m >> 2;
  float ats[16], atd[16];
#pragma unroll
  for (int nt = 0; nt < 16; ++nt) {
    ats[nt] = att_s[m * 16 + nt];
    atd[nt] = att_d[m * 16 + nt];
  }
  _Float16* xf = (_Float16*)xh_h;
#pragma unroll
  for (int r = 0; r < 4; ++r) {
    int orow = rowbase + quad * 4 + r;
    bool valid = orow < N;
    float ps = 0.f, pd = 0.f;
    half8 h0, h1;
#pragma unroll
    for (int nt = 0; nt < 8; ++nt) {
      h0[nt] = (_Float16)acc[nt][r];
      h1[nt] = (_Float16)acc[nt + 8][r];
      ps += acc[nt][r] * ats[nt] + acc[nt + 8][r] * ats[nt + 8];
      pd += acc[nt][r] * atd[nt] + acc[nt + 8][r] * atd[nt + 8];
    }
    if (valid) {
      _Float16* dst = xf + (size_t)orow * HD + m * 16;
      *(half8*)dst = h0;
      *(half8*)(dst + 8) = h1;
    }
    ps += __shfl_xor(ps, 1, 64);
    ps += __shfl_xor(ps, 2, 64);
    pd += __shfl_xor(pd, 1, 64);
    pd += __shfl_xor(pd, 2, 64);
    if (valid && (m & 3) == 0) {
      a_src[(size_t)orow * NHEAD + hh] = ps;
      a_dst[(size_t)orow * NHEAD + hh] = pd;
    }
  }
}

// ---------------------------------------------------------------------------
// Fused softmax + gather-aggregate (R11 dense-array layout — best measured).
// 4 nodes/block, 1 wave/node. Pass 1: online softmax. Pass 2: cooperative
// weights + broadcast + 16 row-gathers in flight.
// ---------------------------------------------------------------------------
__global__ __launch_bounds__(256) void fused_aggregate_kernel(
    const __half* __restrict__ xh_h, const int* __restrict__ rowc,
    const int* __restrict__ row_start, const float* __restrict__ ae4c_l,
    const float* __restrict__ a_src, const float* __restrict__ a_dst,
    const float* __restrict__ cb, const float* __restrict__ gm,
    const float* __restrict__ bt, float inv_std, float* __restrict__ hout,
    int N) {
  int tid = threadIdx.x;
  int n = blockIdx.x * 4 + (tid >> 6);
  if (n >= N) return;
  int lane = tid & 63;
  int s = row_start[n], e = row_start[n + 1];

  int hh1 = lane & 3, j = lane >> 2;
  float based1 = a_dst[n * 4 + hh1];
  float m = -3e38f, ssum = 0.f, aes = 0.f;
  for (int i = s + j; i < e; i += 16) {
    int r = rowc[i];
    float ae = ae4c_l[(size_t)i * 4 + hh1];
    float lg = a_src[r * 4 + hh1] + based1 + ae;
    lg = (lg >= 0.f) ? lg : NEG_SLOPE * lg;
    aes += ae;
    float mn = fmaxf(m, lg);
    ssum = ssum * __expf(m - mn) + __expf(lg - mn);
    m = mn;
  }
#pragma unroll
  for (int off = 4; off < 64; off <<= 1) {
    float m2 = __shfl_xor(m, off, 64);
    float s2 = __shfl_xor(ssum, off, 64);
    aes += __shfl_xor(aes, off, 64);
    float mn = fmaxf(m, m2);
    ssum = ssum * __expf(m - mn) + s2 * __expf(m2 - mn);
    m = mn;
  }
  float dinv = (e > s) ? 1.0f / (float)(e - s) : 1.0f;
  float sl = a_src[n * 4 + hh1] + based1 + aes * dinv;
  sl = (sl >= 0.f) ? sl : NEG_SLOPE * sl;
  float mfin = fmaxf(m, sl);
  float self_e = __expf(sl - mfin);
  float tot = ssum * __expf(m - mfin) + self_e;
  float is = 1.0f / (tot + 1e-16f);
  float selfw = self_e * is;

  int hw = lane >> 4;
  float m_h = __shfl(mfin, hw, 64);
  float is_h = __shfl(is, hw, 64);
  float sw_h = __shfl(selfw, hw, 64);
  float based2 = a_dst[n * 4 + hw];

  int eidx = lane & 15;
  int t = lane;
  int ch = t * 4;
  const half4v* xh4 = (const half4v*)xh_h;

  half4v sv = xh4[(size_t)n * 64 + t];
  float a0 = sw_h * (float)sv[0], a1 = sw_h * (float)sv[1];
  float a2 = sw_h * (float)sv[2], a3 = sw_h * (float)sv[3];

  const int base_src = lane & 48;
  for (int chunk = s; chunk < e; chunk += 16) {
    int myedge = chunk + eidx;
    int r_my = 0;
    float w_my = 0.f;
    if (myedge < e) {
      r_my = rowc[myedge];
      float lg = a_src[r_my * 4 + hw] + based2 + ae4c_l[(size_t)myedge * 4 + hw];
      lg = (lg >= 0.f) ? lg : NEG_SLOPE * lg;
      w_my = __expf(lg - m_h) * is_h;
    }
#pragma unroll
    for (int u = 0; u < 16; ++u) {
      float w = __shfl(w_my, base_src + u, 64);
      int ru = __shfl(r_my, base_src + u, 64);
      half4v xv = xh4[(size_t)ru * 64 + t];
      a0 += w * (float)xv[0];
      a1 += w * (float)xv[1];
      a2 += w * (float)xv[2];
      a3 += w * (float)xv[3];
    }
  }
  float4 outv;
  outv.x = fmaxf((a0 + cb[ch + 0]) * inv_std * gm[ch + 0] + bt[ch + 0], 0.f);
  outv.y = fmaxf((a1 + cb[ch + 1]) * inv_std * gm[ch + 1] + bt[ch + 1], 0.f);
  outv.z = fmaxf((a2 + cb[ch + 2]) * inv_std * gm[ch + 2] + bt[ch + 2], 0.f);
  outv.w = fmaxf((a3 + cb[ch + 3]) * inv_std * gm[ch + 3] + bt[ch + 3], 0.f);
  *(float4*)&hout[(size_t)n * HD + ch] = outv;
}

// ---------------------------------------------------------------------------
// Global mean pool over sorted batch ids. Grid (G, 2), 128 ch per block.
// ---------------------------------------------------------------------------
__global__ __launch_bounds__(128) void pool_kernel(
    const float* __restrict__ h, const int* __restrict__ batch,
    float* __restrict__ out, int N) {
  int g = blockIdx.x;
  int ch = blockIdx.y * 128 + threadIdx.x;
  __shared__ int s_lo, s_hi;
  if (threadIdx.x == 0) {
    int lo = 0, hi = N;
    while (lo < hi) { int mid = (lo + hi) >> 1; if (batch[mid] < g) lo = mid + 1; else hi = mid; }
    s_lo = lo;
    lo = 0; hi = N;
    while (lo < hi) { int mid = (lo + hi) >> 1; if (batch[mid] < g + 1) lo = mid + 1; else hi = mid; }
    s_hi = lo;
  }
  __syncthreads();
  int lo = s_lo, hi = s_hi;
  float acc = 0.f;
  for (int n = lo; n < hi; ++n) acc += h[(size_t)n * HD + ch];
  int cnt = hi - lo;
  out[(size_t)g * HD + ch] = acc / (float)(cnt > 0 ? cnt : 1);
}

// ---------------------------------------------------------------------------
extern "C" void kernel_launch(void* const* d_in, const int* in_sizes, int n_in,
                              void* d_out, int out_size, void* d_ws, size_t ws_size,
                              hipStream_t stream) {
  const float* x = (const float*)d_in[0];
  const int* ei = (const int*)d_in[1];
  const float* edge_attr = (const float*)d_in[2];
  const int* batch = (const int*)d_in[3];
  const float* Wn = (const float*)d_in[4];
  const float* bn_b = (const float*)d_in[5];
  const float* We = (const float*)d_in[6];
  const float* be_b = (const float*)d_in[7];
  const float* lin_w = (const float*)d_in[8];
  const float* att_src = (const float*)d_in[9];
  const float* att_dst = (const float*)d_in[10];
  const float* lin_edge_w = (const float*)d_in[11];
  const float* att_edge = (const float*)d_in[12];
  const float* conv_bias = (const float*)d_in[13];
  const float* gamma = (const float*)d_in[14];
  const float* beta = (const float*)d_in[15];

  const int N = in_sizes[3];
  const int E = in_sizes[1] / 2;
  const int G = out_size / HD;
  const int* row = ei;
  const int* col = ei + E;

  char* ws = (char*)d_ws;
  size_t off = 0;
  auto alloc = [&](size_t bytes) -> char* {
    char* p = ws + off;
    off += (bytes + 255) & ~(size_t)255;
    return p;
  };
  float* h = (float*)alloc((size_t)N * HD * 4);
  __half* xh_h = (__half*)alloc((size_t)N * HD * 2);
  float* a_src = (float*)alloc((size_t)N * NHEAD * 4);
  float* a_dst = (float*)alloc((size_t)N * NHEAD * 4);
  float* ae4c_all = (float*)alloc((size_t)NLAYER * E * NHEAD * 4);
  int* deg = (int*)alloc((size_t)N * 4);
  int* row_start = (int*)alloc((size_t)(N + 1) * 4);
  int* cursor = (int*)alloc((size_t)N * 4);
  int* rowc = (int*)alloc((size_t)E * 4);
  int* tsum = (int*)alloc(4096);
  int* toff = (int*)alloc(4096);
  float* Wc = (float*)alloc(64 * 4);
  float* bc = (float*)alloc(16 * 4);
  _Float16* Bf_hi = (_Float16*)alloc((size_t)NLAYER * HD * HD * 2);

  hipMemsetAsync(deg, 0, (size_t)N * 4, stream);
  hipMemsetAsync(cursor, 0, (size_t)N * 4, stream);

  node_embed_kernel<<<N, 256, 0, stream>>>(x, Wn, bn_b, h, N);
  precompute_wc_kernel<<<12, 256, 0, stream>>>(lin_edge_w, att_edge, We, be_b, Wc, bc);
  conv_bfrag_kernel<<<NLAYER * 128, 64, 0, stream>>>(lin_w, Bf_hi);
  count_deg_kernel<<<(E + 255) / 256, 256, 0, stream>>>(col, deg, E);
  int T = (N + 255) / 256;
  tile_sums_kernel<<<T, 256, 0, stream>>>(deg, tsum, N);
  scan_tsums_kernel<<<1, 64, 0, stream>>>(tsum, toff, T);
  scan_local_kernel<<<T, 256, 0, stream>>>(deg, toff, row_start, N, E);
  scatter_csr_ae_kernel<<<(E + 255) / 256, 256, 0, stream>>>(
      row, col, edge_attr, row_start, cursor, rowc, Wc, bc, ae4c_all, E);

  const float inv_std = 1.0f / sqrtf(1.0f + 1e-5f);
  for (int l = 0; l < NLAYER; ++l) {
    mfma_gemm_fused_kernel<<<(N + 127) / 128, 512, 0, stream>>>(
        h, Bf_hi + (size_t)l * HD * HD,
        att_src + l * HD, att_dst + l * HD, xh_h, a_src, a_dst, N);
    fused_aggregate_kernel<<<(N + 3) / 4, 256, 0, stream>>>(
        xh_h, rowc, row_start, ae4c_all + (size_t)l * E * NHEAD, a_src, a_dst,
        conv_bias + l * HD, gamma + l * HD, beta + l * HD, inv_std, h, N);
  }
  dim3 pg(G, 2);
  pool_kernel<<<pg, 128, 0, stream>>>(h, batch, (float*)d_out, N);
}

// Round 16
// 558.517 us; speedup vs baseline: 1.2027x; 1.0291x over previous
//
#include <hip/hip_runtime.h>
#include <hip/hip_fp16.h>
#include <math.h>

#define HD 256
#define NHEAD 4
#define CH 64
#define NLAYER 3
#define NEG_SLOPE 0.2f

typedef __attribute__((ext_vector_type(8))) _Float16 half8;
typedef __attribute__((ext_vector_type(4))) _Float16 half4v;
typedef __attribute__((ext_vector_type(4))) float float4v;

// ---------------------------------------------------------------------------
// h0 = x @ Wn + bn_b      (x: [N,9], Wn: [9,256]) — 8 nodes per block
// ---------------------------------------------------------------------------
__global__ __launch_bounds__(256) void node_embed_kernel(
    const float* __restrict__ x, const float* __restrict__ Wn,
    const float* __restrict__ bn_b, float* __restrict__ h, int N) {
  int base = blockIdx.x * 8;
  int c = threadIdx.x;
  __shared__ float xs[8][9];
  int nn = N - base;
  if (nn > 8) nn = 8;
  if (c < nn * 9) xs[c / 9][c % 9] = x[(size_t)base * 9 + c];
  __syncthreads();
  float b = bn_b[c];
  for (int i = 0; i < nn; ++i) {
    float v = b;
#pragma unroll
    for (int k = 0; k < 9; ++k) v += xs[i][k] * Wn[k * HD + c];
    h[(size_t)(base + i) * HD + c] = v;
  }
}

// ---------------------------------------------------------------------------
// Fold edge path: Wc[5][12] = We @ w_eff,  bc[12] = be_b @ w_eff.
// 12 blocks, one per (layer, head).
// ---------------------------------------------------------------------------
__global__ __launch_bounds__(256) void precompute_wc_kernel(
    const float* __restrict__ lin_edge_w, const float* __restrict__ att_edge,
    const float* __restrict__ We, const float* __restrict__ be_b,
    float* __restrict__ Wc, float* __restrict__ bc) {
  int lh = blockIdx.x;           // 0..11 = l*4+hh
  int l = lh >> 2, hh = lh & 3;
  __shared__ float weff[256];
  int j = threadIdx.x;
  const float* lw = lin_edge_w + (size_t)l * HD * HD + (size_t)j * HD + hh * CH;
  const float* ae = att_edge + l * HD + hh * CH;
  float s = 0.f;
#pragma unroll 8
  for (int c = 0; c < CH; ++c) s += lw[c] * ae[c];
  weff[j] = s;
  __syncthreads();
  if (j < 5) {
    float acc = 0.f;
    for (int t = 0; t < 256; ++t) acc += We[j * HD + t] * weff[t];
    Wc[j * 12 + lh] = acc;
  } else if (j == 5) {
    float acc = 0.f;
    for (int t = 0; t < 256; ++t) acc += be_b[t] * weff[t];
    bc[lh] = acc;
  }
}

// ---------------------------------------------------------------------------
// Repack lin_w into MFMA B-fragment order, fp16.
// Head-split col map: fragment (l,kt,ntg), lane -> col n = (ntg>=8?128:0)
// + (lane&15)*8 + (ntg&7). Lane m's 8 cols are consecutive, inside ONE head.
// ---------------------------------------------------------------------------
__global__ __launch_bounds__(64) void conv_bfrag_kernel(
    const float* __restrict__ lin_w, _Float16* __restrict__ Bf_hi) {
  int bid = blockIdx.x;            // l*128 + kt*16 + ntg
  int l = bid >> 7;
  int kt = (bid >> 4) & 7, ntg = bid & 15;
  int lane = threadIdx.x;
  const float* B = lin_w + (size_t)l * HD * HD;
  size_t base = ((size_t)bid * 64 + lane) * 8;
  int k0 = kt * 32 + (lane >> 4) * 8;
  int n = ((ntg >= 8) ? 128 : 0) + (lane & 15) * 8 + (ntg & 7);
#pragma unroll
  for (int j = 0; j < 8; ++j) {
    Bf_hi[base + j] = (_Float16)B[(size_t)(k0 + j) * HD + n];
  }
}

// ---------------------------------------------------------------------------
// CSR build by destination (col)
// ---------------------------------------------------------------------------
__global__ __launch_bounds__(256) void count_deg_kernel(
    const int* __restrict__ col, int* __restrict__ deg, int E) {
  int e = blockIdx.x * 256 + threadIdx.x;
  if (e < E) atomicAdd(&deg[col[e]], 1);
}

__global__ __launch_bounds__(256) void tile_sums_kernel(
    const int* __restrict__ deg, int* __restrict__ tsum, int N) {
  __shared__ int red[256];
  int i = blockIdx.x * 256 + threadIdx.x;
  red[threadIdx.x] = (i < N) ? deg[i] : 0;
  __syncthreads();
  for (int off = 128; off > 0; off >>= 1) {
    if (threadIdx.x < off) red[threadIdx.x] += red[threadIdx.x + off];
    __syncthreads();
  }
  if (threadIdx.x == 0) tsum[blockIdx.x] = red[0];
}

__global__ __launch_bounds__(64) void scan_tsums_kernel(
    const int* __restrict__ tsum, int* __restrict__ toff, int T) {
  int lane = threadIdx.x;
  int carry = 0;
  for (int base = 0; base < T; base += 64) {
    int i = base + lane;
    int orig = (i < T) ? tsum[i] : 0;
    int v = orig;
#pragma unroll
    for (int off = 1; off < 64; off <<= 1) {
      int t = __shfl_up(v, off, 64);
      if (lane >= off) v += t;
    }
    if (i < T) toff[i] = carry + v - orig;
    carry += __shfl(v, 63, 64);
  }
}

__global__ __launch_bounds__(256) void scan_local_kernel(
    const int* __restrict__ deg, const int* __restrict__ toff,
    int* __restrict__ row_start, int N, int E) {
  __shared__ int buf[256];
  int i = blockIdx.x * 256 + threadIdx.x;
  int v = (i < N) ? deg[i] : 0;
  buf[threadIdx.x] = v;
  __syncthreads();
  for (int off = 1; off < 256; off <<= 1) {
    int t = (threadIdx.x >= off) ? buf[threadIdx.x - off] : 0;
    __syncthreads();
    buf[threadIdx.x] += t;
    __syncthreads();
  }
  if (i < N) row_start[i] = toff[blockIdx.x] + buf[threadIdx.x] - v;
  if (blockIdx.x == 0 && threadIdx.x == 0) row_start[N] = E;
}

// ---------------------------------------------------------------------------
// CSR scatter + fused per-edge a_e for ALL 3 layers (R11 layout — best
// measured: dense rowc + ae4c_all arrays, single kernel).
// ---------------------------------------------------------------------------
__global__ __launch_bounds__(256) void scatter_csr_ae_kernel(
    const int* __restrict__ row, const int* __restrict__ col,
    const float* __restrict__ edge_attr, const int* __restrict__ row_start,
    int* __restrict__ cursor, int* __restrict__ rowc,
    const float* __restrict__ Wc, const float* __restrict__ bc,
    float* __restrict__ ae4c_all, int E) {
  __shared__ float sWc[60];
  __shared__ float sbc[12];
  int t = threadIdx.x;
  if (t < 60) sWc[t] = Wc[t];
  if (t < 12) sbc[t] = bc[t];
  __syncthreads();
  int e = blockIdx.x * 256 + t;
  if (e >= E) return;
  int c = col[e];
  int p = atomicAdd(&cursor[c], 1);
  int slot = row_start[c] + p;
  rowc[slot] = row[e];
  float ea[5];
#pragma unroll
  for (int k = 0; k < 5; ++k) ea[k] = edge_attr[(size_t)e * 5 + k];
#pragma unroll
  for (int l = 0; l < NLAYER; ++l) {
    float av[NHEAD];
#pragma unroll
    for (int hh = 0; hh < NHEAD; ++hh) {
      int lh = l * NHEAD + hh;
      float s = sbc[lh];
#pragma unroll
      for (int k = 0; k < 5; ++k) s += ea[k] * sWc[k * 12 + lh];
      av[hh] = s;
    }
    *(float4*)(ae4c_all + ((size_t)l * E + slot) * 4) =
        make_float4(av[0], av[1], av[2], av[3]);
  }
}

// ---------------------------------------------------------------------------
// MFMA GEMM (A fp32 hi+lo; B fp16), head-split over grid y: block y computes
// cols [y*128, y*128+128). 782 blocks x 8 waves = 2x machine fill vs full-N
// blocks; acc 32 VGPR, LDS 8KB/kt. Each lane owns 8 consecutive cols in one
// head (hh = y*2 + (m>>3)) -> a_src/a_dst written once, no atomics.
// ---------------------------------------------------------------------------
__global__ __launch_bounds__(512) void mfma_gemm_fused_kernel(
    const float* __restrict__ A, const _Float16* __restrict__ Bf_hi,
    const float* __restrict__ att_s, const float* __restrict__ att_d,
    __half* __restrict__ xh_h, float* __restrict__ a_src,
    float* __restrict__ a_dst, int N) {
  __shared__ _Float16 sBh[4096];  // 8 KB: kt-slice of this block's col half
  const int tid = threadIdx.x;
  const int wave = tid >> 6, lane = tid & 63;
  const int m = lane & 15, quad = lane >> 4;
  const int y = blockIdx.y;
  const int rowbase = blockIdx.x * 128 + wave * 16;
  const int arow = rowbase + m;
  const int arowc = (arow < N) ? arow : (N - 1);

  float4v acc[8];
#pragma unroll
  for (int nt = 0; nt < 8; ++nt) acc[nt] = (float4v){0.f, 0.f, 0.f, 0.f};

  for (int kt = 0; kt < 8; ++kt) {
    __syncthreads();  // previous iteration's LDS reads done
    {
      const float4* gh = (const float4*)(Bf_hi + ((size_t)kt * 16 + y * 8) * 512);
      ((float4*)sBh)[tid] = gh[tid];
    }
    const float* ap = A + (size_t)arowc * HD + kt * 32 + quad * 8;
    float4 av0 = *(const float4*)(ap);
    float4 av1 = *(const float4*)(ap + 4);
    float af[8] = {av0.x, av0.y, av0.z, av0.w, av1.x, av1.y, av1.z, av1.w};
    half8 ahi, alo;
#pragma unroll
    for (int j = 0; j < 8; ++j) {
      _Float16 hi = (_Float16)af[j];
      ahi[j] = hi;
      alo[j] = (_Float16)(af[j] - (float)hi);
    }
    __syncthreads();  // staging complete
#pragma unroll
    for (int nt = 0; nt < 8; ++nt) {
      half8 bhi = *(const half8*)&sBh[nt * 512 + lane * 8];
      acc[nt] = __builtin_amdgcn_mfma_f32_16x16x32_f16(ahi, bhi, acc[nt], 0, 0, 0);
      acc[nt] = __builtin_amdgcn_mfma_f32_16x16x32_f16(alo, bhi, acc[nt], 0, 0, 0);
    }
  }

  // lane's 8 cols: y*128 + m*8 + nt — all in head hh = y*2 + (m>>3)
  const int hh = y * 2 + (m >> 3);
  const int colbase = y * 128 + m * 8;
  float ats[8], atd[8];
#pragma unroll
  for (int nt = 0; nt < 8; ++nt) {
    ats[nt] = att_s[colbase + nt];
    atd[nt] = att_d[colbase + nt];
  }
  _Float16* xf = (_Float16*)xh_h;
#pragma unroll
  for (int r = 0; r < 4; ++r) {
    int orow = rowbase + quad * 4 + r;
    bool valid = orow < N;
    float ps = 0.f, pd = 0.f;
    half8 h0;
#pragma unroll
    for (int nt = 0; nt < 8; ++nt) {
      h0[nt] = (_Float16)acc[nt][r];
      ps += acc[nt][r] * ats[nt];
      pd += acc[nt][r] * atd[nt];
    }
    if (valid) {
      *(half8*)(xf + (size_t)orow * HD + colbase) = h0;
    }
    // reduce over the 8 lanes (m bits 0..2) sharing this head
    ps += __shfl_xor(ps, 1, 64);
    ps += __shfl_xor(ps, 2, 64);
    ps += __shfl_xor(ps, 4, 64);
    pd += __shfl_xor(pd, 1, 64);
    pd += __shfl_xor(pd, 2, 64);
    pd += __shfl_xor(pd, 4, 64);
    if (valid && (m & 7) == 0) {
      a_src[(size_t)orow * NHEAD + hh] = ps;
      a_dst[(size_t)orow * NHEAD + hh] = pd;
    }
  }
}

// ---------------------------------------------------------------------------
// Fused softmax + gather-aggregate (R11 dense-array layout — best measured).
// 4 nodes/block, 1 wave/node. Pass 1: online softmax. Pass 2: cooperative
// weights + broadcast + 16 row-gathers in flight.
// ---------------------------------------------------------------------------
__global__ __launch_bounds__(256) void fused_aggregate_kernel(
    const __half* __restrict__ xh_h, const int* __restrict__ rowc,
    const int* __restrict__ row_start, const float* __restrict__ ae4c_l,
    const float* __restrict__ a_src, const float* __restrict__ a_dst,
    const float* __restrict__ cb, const float* __restrict__ gm,
    const float* __restrict__ bt, float inv_std, float* __restrict__ hout,
    int N) {
  int tid = threadIdx.x;
  int n = blockIdx.x * 4 + (tid >> 6);
  if (n >= N) return;
  int lane = tid & 63;
  int s = row_start[n], e = row_start[n + 1];

  int hh1 = lane & 3, j = lane >> 2;
  float based1 = a_dst[n * 4 + hh1];
  float m = -3e38f, ssum = 0.f, aes = 0.f;
  for (int i = s + j; i < e; i += 16) {
    int r = rowc[i];
    float ae = ae4c_l[(size_t)i * 4 + hh1];
    float lg = a_src[r * 4 + hh1] + based1 + ae;
    lg = (lg >= 0.f) ? lg : NEG_SLOPE * lg;
    aes += ae;
    float mn = fmaxf(m, lg);
    ssum = ssum * __expf(m - mn) + __expf(lg - mn);
    m = mn;
  }
#pragma unroll
  for (int off = 4; off < 64; off <<= 1) {
    float m2 = __shfl_xor(m, off, 64);
    float s2 = __shfl_xor(ssum, off, 64);
    aes += __shfl_xor(aes, off, 64);
    float mn = fmaxf(m, m2);
    ssum = ssum * __expf(m - mn) + s2 * __expf(m2 - mn);
    m = mn;
  }
  float dinv = (e > s) ? 1.0f / (float)(e - s) : 1.0f;
  float sl = a_src[n * 4 + hh1] + based1 + aes * dinv;
  sl = (sl >= 0.f) ? sl : NEG_SLOPE * sl;
  float mfin = fmaxf(m, sl);
  float self_e = __expf(sl - mfin);
  float tot = ssum * __expf(m - mfin) + self_e;
  float is = 1.0f / (tot + 1e-16f);
  float selfw = self_e * is;

  int hw = lane >> 4;
  float m_h = __shfl(mfin, hw, 64);
  float is_h = __shfl(is, hw, 64);
  float sw_h = __shfl(selfw, hw, 64);
  float based2 = a_dst[n * 4 + hw];

  int eidx = lane & 15;
  int t = lane;
  int ch = t * 4;
  const half4v* xh4 = (const half4v*)xh_h;

  half4v sv = xh4[(size_t)n * 64 + t];
  float a0 = sw_h * (float)sv[0], a1 = sw_h * (float)sv[1];
  float a2 = sw_h * (float)sv[2], a3 = sw_h * (float)sv[3];

  const int base_src = lane & 48;
  for (int chunk = s; chunk < e; chunk += 16) {
    int myedge = chunk + eidx;
    int r_my = 0;
    float w_my = 0.f;
    if (myedge < e) {
      r_my = rowc[myedge];
      float lg = a_src[r_my * 4 + hw] + based2 + ae4c_l[(size_t)myedge * 4 + hw];
      lg = (lg >= 0.f) ? lg : NEG_SLOPE * lg;
      w_my = __expf(lg - m_h) * is_h;
    }
#pragma unroll
    for (int u = 0; u < 16; ++u) {
      float w = __shfl(w_my, base_src + u, 64);
      int ru = __shfl(r_my, base_src + u, 64);
      half4v xv = xh4[(size_t)ru * 64 + t];
      a0 += w * (float)xv[0];
      a1 += w * (float)xv[1];
      a2 += w * (float)xv[2];
      a3 += w * (float)xv[3];
    }
  }
  float4 outv;
  outv.x = fmaxf((a0 + cb[ch + 0]) * inv_std * gm[ch + 0] + bt[ch + 0], 0.f);
  outv.y = fmaxf((a1 + cb[ch + 1]) * inv_std * gm[ch + 1] + bt[ch + 1], 0.f);
  outv.z = fmaxf((a2 + cb[ch + 2]) * inv_std * gm[ch + 2] + bt[ch + 2], 0.f);
  outv.w = fmaxf((a3 + cb[ch + 3]) * inv_std * gm[ch + 3] + bt[ch + 3], 0.f);
  *(float4*)&hout[(size_t)n * HD + ch] = outv;
}

// ---------------------------------------------------------------------------
// Global mean pool over sorted batch ids. Grid (G, 2), 128 ch per block.
// ---------------------------------------------------------------------------
__global__ __launch_bounds__(128) void pool_kernel(
    const float* __restrict__ h, const int* __restrict__ batch,
    float* __restrict__ out, int N) {
  int g = blockIdx.x;
  int ch = blockIdx.y * 128 + threadIdx.x;
  __shared__ int s_lo, s_hi;
  if (threadIdx.x == 0) {
    int lo = 0, hi = N;
    while (lo < hi) { int mid = (lo + hi) >> 1; if (batch[mid] < g) lo = mid + 1; else hi = mid; }
    s_lo = lo;
    lo = 0; hi = N;
    while (lo < hi) { int mid = (lo + hi) >> 1; if (batch[mid] < g + 1) lo = mid + 1; else hi = mid; }
    s_hi = lo;
  }
  __syncthreads();
  int lo = s_lo, hi = s_hi;
  float acc = 0.f;
  for (int n = lo; n < hi; ++n) acc += h[(size_t)n * HD + ch];
  int cnt = hi - lo;
  out[(size_t)g * HD + ch] = acc / (float)(cnt > 0 ? cnt : 1);
}

// ---------------------------------------------------------------------------
extern "C" void kernel_launch(void* const* d_in, const int* in_sizes, int n_in,
                              void* d_out, int out_size, void* d_ws, size_t ws_size,
                              hipStream_t stream) {
  const float* x = (const float*)d_in[0];
  const int* ei = (const int*)d_in[1];
  const float* edge_attr = (const float*)d_in[2];
  const int* batch = (const int*)d_in[3];
  const float* Wn = (const float*)d_in[4];
  const float* bn_b = (const float*)d_in[5];
  const float* We = (const float*)d_in[6];
  const float* be_b = (const float*)d_in[7];
  const float* lin_w = (const float*)d_in[8];
  const float* att_src = (const float*)d_in[9];
  const float* att_dst = (const float*)d_in[10];
  const float* lin_edge_w = (const float*)d_in[11];
  const float* att_edge = (const float*)d_in[12];
  const float* conv_bias = (const float*)d_in[13];
  const float* gamma = (const float*)d_in[14];
  const float* beta = (const float*)d_in[15];

  const int N = in_sizes[3];
  const int E = in_sizes[1] / 2;
  const int G = out_size / HD;
  const int* row = ei;
  const int* col = ei + E;

  char* ws = (char*)d_ws;
  size_t off = 0;
  auto alloc = [&](size_t bytes) -> char* {
    char* p = ws + off;
    off += (bytes + 255) & ~(size_t)255;
    return p;
  };
  float* h = (float*)alloc((size_t)N * HD * 4);
  __half* xh_h = (__half*)alloc((size_t)N * HD * 2);
  float* a_src = (float*)alloc((size_t)N * NHEAD * 4);
  float* a_dst = (float*)alloc((size_t)N * NHEAD * 4);
  float* ae4c_all = (float*)alloc((size_t)NLAYER * E * NHEAD * 4);
  int* deg = (int*)alloc((size_t)N * 4);
  int* row_start = (int*)alloc((size_t)(N + 1) * 4);
  int* cursor = (int*)alloc((size_t)N * 4);
  int* rowc = (int*)alloc((size_t)E * 4);
  int* tsum = (int*)alloc(4096);
  int* toff = (int*)alloc(4096);
  float* Wc = (float*)alloc(64 * 4);
  float* bc = (float*)alloc(16 * 4);
  _Float16* Bf_hi = (_Float16*)alloc((size_t)NLAYER * HD * HD * 2);

  hipMemsetAsync(deg, 0, (size_t)N * 4, stream);
  hipMemsetAsync(cursor, 0, (size_t)N * 4, stream);

  node_embed_kernel<<<(N + 7) / 8, 256, 0, stream>>>(x, Wn, bn_b, h, N);
  precompute_wc_kernel<<<12, 256, 0, stream>>>(lin_edge_w, att_edge, We, be_b, Wc, bc);
  conv_bfrag_kernel<<<NLAYER * 128, 64, 0, stream>>>(lin_w, Bf_hi);
  count_deg_kernel<<<(E + 255) / 256, 256, 0, stream>>>(col, deg, E);
  int T = (N + 255) / 256;
  tile_sums_kernel<<<T, 256, 0, stream>>>(deg, tsum, N);
  scan_tsums_kernel<<<1, 64, 0, stream>>>(tsum, toff, T);
  scan_local_kernel<<<T, 256, 0, stream>>>(deg, toff, row_start, N, E);
  scatter_csr_ae_kernel<<<(E + 255) / 256, 256, 0, stream>>>(
      row, col, edge_attr, row_start, cursor, rowc, Wc, bc, ae4c_all, E);

  const float inv_std = 1.0f / sqrtf(1.0f + 1e-5f);
  for (int l = 0; l < NLAYER; ++l) {
    dim3 gg((N + 127) / 128, 2);
    mfma_gemm_fused_kernel<<<gg, 512, 0, stream>>>(
        h, Bf_hi + (size_t)l * HD * HD,
        att_src + l * HD, att_dst + l * HD, xh_h, a_src, a_dst, N);
    fused_aggregate_kernel<<<(N + 3) / 4, 256, 0, stream>>>(
        xh_h, rowc, row_start, ae4c_all + (size_t)l * E * NHEAD, a_src, a_dst,
        conv_bias + l * HD, gamma + l * HD, beta + l * HD, inv_std, h, N);
  }
  dim3 pg(G, 2);
  pool_kernel<<<pg, 128, 0, stream>>>(h, batch, (float*)d_out, N);
}